// Round 5
// baseline (351.144 us; speedup 1.0000x reference)
//
#include <hip/hip_runtime.h>
#include <stdint.h>

#define B_ 4
#define L_ 4096
#define H_ 8
#define D_ 64
#define S_ 45
#define U_ 45
#define BH_ 32
#define KC_ 16                     // split-k chunks (256 keys each)
#define STRIDE_ (H_*D_)            // 512 floats between consecutive l
#define BSTR_ ((size_t)L_*H_*D_)   // 2097152 floats per batch

// index_sample declared int64 in the reference; harness may pass int32 or int64.
__device__ __forceinline__ bool detect_idx64(const int* idxp){
    bool z = true;
    #pragma unroll
    for (int i = 1; i < 32; i += 2) z = z && (idxp[i] == 0);
    return z;
}

// Nontemporal float4 load (HIP float4 is a struct; go through ext_vector).
typedef float v4f_ __attribute__((ext_vector_type(4)));
__device__ __forceinline__ float4 ntload4(const float4* p){
    v4f_ v = __builtin_nontemporal_load((const v4f_*)p);
    return make_float4(v.x, v.y, v.z, v.w);
}

// ---------- kernel A: M[bh][q] = max_s(dot) - sum_s(dot)/L ----------
// FULL 8-head-fused gather: one sample row = K[b, ki, :, :] = 2 KB contiguous.
// index_sample is shared across (b,h), so one gather serves all 8 heads.
// One 32-lane half-wave owns one q; each sample row = 4 wave-instructions,
// each a fully dense contiguous 512 B segment (vs 4 scattered 256 B segments
// before). Bytes & line count invariant (1.51 GB); vmem request count per
// byte HALVED. Discriminates request-rate-bound vs byte-plateau-bound.
// Lane map per instr c (c=0..3): lane l32 reads floats c*128 + l32*4 .. +3
// -> head 2c + (l32>>4), dims (l32&15)*4 .. +3.
__global__ __launch_bounds__(256) void kM(const float* __restrict__ Qb,
                                          const float* __restrict__ Kb,
                                          const int* __restrict__ idxp,
                                          float* __restrict__ Mout){
    int g = blockIdx.x;                 // 0..2047
    int b  = g & 3;                     // one b per XCD (round-robin g%8)
    int q0 = (g >> 2) * 8;              // 8 q per block
    bool idx64 = detect_idx64(idxp);

    __shared__ int lidx[8*S_];          // 1.44 KB: this block's 8 q x 45 idx
    for (int i = threadIdx.x; i < 8*S_; i += 256)
        lidx[i] = idx64 ? __builtin_nontemporal_load(&idxp[2*(q0*S_ + i)])
                        : __builtin_nontemporal_load(&idxp[q0*S_ + i]);
    __syncthreads();

    int lane = threadIdx.x & 63;
    int w    = threadIdx.x >> 6;        // wave 0..3
    int hw   = lane >> 5;               // half-wave 0/1: one q each
    int l32  = lane & 31;
    int c16  = l32 >> 4;                // head-parity subgroup within half-wave
    int l16  = lane & 15;
    int ql   = w*2 + hw;                // 0..7
    int q    = q0 + ql;

    // Q fragments: same lane map as K row (full 8-head row, 2 KB)
    const float4* qr = (const float4*)(Qb + (size_t)b*BSTR_ + (size_t)q*STRIDE_);
    float4 qf0 = ntload4(qr + 0*32 + l32);   // heads 0/1
    float4 qf1 = ntload4(qr + 1*32 + l32);   // heads 2/3
    float4 qf2 = ntload4(qr + 2*32 + l32);   // heads 4/5
    float4 qf3 = ntload4(qr + 3*32 + l32);   // heads 6/7

    const float* kbase = Kb + (size_t)b*BSTR_;
    // lanes l16<8 accumulate heads {c16, 2+c16}; l16>=8 heads {4+c16, 6+c16}
    float mxa = -1e30f, mxb = -1e30f, sma = 0.f, smb = 0.f;
    const int* myIdx = &lidx[ql*S_];

    #pragma unroll 3
    for (int s = 0; s < S_; s++){
        int ki = myIdx[s];              // broadcast within half-wave
        const float4* kr = (const float4*)(kbase + (size_t)ki*STRIDE_);
        float4 k0 = kr[0*32 + l32];
        float4 k1 = kr[1*32 + l32];
        float4 k2 = kr[2*32 + l32];
        float4 k3 = kr[3*32 + l32];
        float p0 = qf0.x*k0.x; p0 = fmaf(qf0.y,k0.y,p0); p0 = fmaf(qf0.z,k0.z,p0); p0 = fmaf(qf0.w,k0.w,p0);
        float p1 = qf1.x*k1.x; p1 = fmaf(qf1.y,k1.y,p1); p1 = fmaf(qf1.z,k1.z,p1); p1 = fmaf(qf1.w,k1.w,p1);
        float p2 = qf2.x*k2.x; p2 = fmaf(qf2.y,k2.y,p2); p2 = fmaf(qf2.z,k2.z,p2); p2 = fmaf(qf2.w,k2.w,p2);
        float p3 = qf3.x*k3.x; p3 = fmaf(qf3.y,k3.y,p3); p3 = fmaf(qf3.z,k3.z,p3); p3 = fmaf(qf3.w,k3.w,p3);
        // fold xor-8 (pairs within each 16-lane group)
        float u0 = p0 + __shfl_xor(p0, 8);
        float u1 = p1 + __shfl_xor(p1, 8);
        float u2 = p2 + __shfl_xor(p2, 8);
        float u3 = p3 + __shfl_xor(p3, 8);
        // lane specialization: low 8 lanes carry c={0,1}, high 8 carry c={2,3}
        float va = (l16 < 8) ? u0 : u2;
        float vb = (l16 < 8) ? u1 : u3;
        #pragma unroll
        for (int off = 1; off < 8; off <<= 1){
            va += __shfl_xor(va, off);
            vb += __shfl_xor(vb, off);
        }
        mxa = fmaxf(mxa, va); sma += va;
        mxb = fmaxf(mxb, vb); smb += vb;
    }
    // writers: l32 in {0,8,16,24}. head(a) = ((l32>>3)&1)*4 + c16, head(b) = +2.
    if ((l32 & 7) == 0){
        int hsel = ((l32 >> 3) & 1)*4 + c16;
        __builtin_nontemporal_store(mxa - sma*(1.0f/L_),
            &Mout[(size_t)(b*8 + hsel)*L_ + q]);
        __builtin_nontemporal_store(mxb - smb*(1.0f/L_),
            &Mout[(size_t)(b*8 + hsel + 2)*L_ + q]);
    }
}

// ---------- fused top-45 per (b,h) + selRow map + mean zero ----------
__global__ __launch_bounds__(512) void kTopF(const float* __restrict__ M,
                                             int* __restrict__ Mtop,
                                             float* __restrict__ meanZ,
                                             int* __restrict__ selRow){
    int bh = blockIdx.x;
    int t = threadIdx.x;
    if (t < 64) meanZ[bh*64 + t] = 0.f;
    for (int j = t; j < L_; j += 512) selRow[(size_t)bh*L_ + j] = 0;

    __shared__ float cV[8*U_];
    __shared__ int   cI[8*U_];
    int wv = t >> 6, lane = t & 63;      // wv = segment 0..7
    const float* Mr = M + (size_t)bh*L_ + wv*512;
    float v[8];
    #pragma unroll
    for (int j = 0; j < 8; j++) v[j] = Mr[lane + 64*j];

    for (int it = 0; it < U_; it++){
        float best = -1e30f; int bidx = 0x7fffffff;
        #pragma unroll
        for (int j = 0; j < 8; j++){
            int id = lane + 64*j;
            if (v[j] > best){ best = v[j]; bidx = id; }   // ascending id scan
        }
        #pragma unroll
        for (int off = 1; off < 64; off <<= 1){
            float ov = __shfl_xor(best, off); int oi = __shfl_xor(bidx, off);
            if (ov > best || (ov == best && oi < bidx)){ best = ov; bidx = oi; }
        }
        if (lane == 0){ cV[wv*U_ + it] = best; cI[wv*U_ + it] = wv*512 + bidx; }
        if (lane == (bidx & 63)) v[bidx >> 6] = -1e30f;
    }
    __syncthreads();
    if (t < 64){
        float v2[6]; int id2[6];
        #pragma unroll
        for (int j = 0; j < 6; j++){
            int slot = t + 64*j;
            if (slot < 8*U_){ v2[j] = cV[slot]; id2[j] = cI[slot]; }
            else            { v2[j] = -1e30f;  id2[j] = 0x7fffffff; }
        }
        for (int it = 0; it < U_; it++){
            float best = -1e30f; int bidx = 0x7fffffff; int bj = 0;
            #pragma unroll
            for (int j = 0; j < 6; j++){
                if (v2[j] > best || (v2[j] == best && id2[j] < bidx)){
                    best = v2[j]; bidx = id2[j]; bj = j;
                }
            }
            float myBest = best; int myIdx = bidx;
            #pragma unroll
            for (int off = 1; off < 64; off <<= 1){
                float ov = __shfl_xor(best, off); int oi = __shfl_xor(bidx, off);
                if (ov > best || (ov == best && oi < bidx)){ best = ov; bidx = oi; }
            }
            if (t == 0){
                Mtop[bh*U_ + it] = bidx;
                selRow[(size_t)bh*L_ + bidx] = it + 1;
            }
            if (myBest == best && myIdx == bidx) v2[bj] = -1e30f;  // unique owner
        }
    }
}

// ---------- fused flash split-k+u: scores + softmax partials + PV + V-sum ----------
// Grid (kc=16, bh=32, uh=2) = 1024 blocks, 256 threads, ~25 KB LDS.
// Phase 3 is d-major and shuffle-free: lane = output column d, wave owns 6 u
// rows, k-reduction is thread-local. P reads are wave-uniform ds_read_b128
// (broadcast, ~1-2 DS cyc) instead of per-lane scattered reads + 576 shuffles.
__global__ __launch_bounds__(256) void kAttnPart(const float* __restrict__ Qb,
                                                 const float* __restrict__ Kb,
                                                 const float* __restrict__ Vb,
                                                 const int*   __restrict__ Mtop,
                                                 float* __restrict__ Opart,
                                                 float* __restrict__ mlG,
                                                 float* __restrict__ mean){
    int bh = blockIdx.y, b = bh >> 3, h = bh & 7;
    int kc = blockIdx.x, uh = blockIdx.z;
    int u0 = uh ? 23 : 0;
    int nu = uh ? 22 : 23;
    int t = threadIdx.x;
    __shared__ float S[24][260];          // 24.4 KB (rows >= nu zeroed scratch)
    __shared__ int   qidx[23];

    if (t < nu) qidx[t] = Mtop[bh*U_ + u0 + t];
    // zero scratch rows nu..23 so phase-3 over-read rows contribute 0 (no NaN)
    for (int i = t; i < (24 - nu)*260; i += 256) (&S[nu][0])[i] = 0.f;
    __syncthreads();

    // Phase 1: scores for this block's 256 keys, its nu queries.
    int k = kc*256 + t;
    float4 kf[16];
    const float4* K4 = (const float4*)(Kb + (size_t)b*BSTR_ + (size_t)k*STRIDE_ + h*D_);
    #pragma unroll
    for (int c = 0; c < 16; c++) kf[c] = K4[c];
    for (int u = 0; u < nu; u++){
        int qi = __builtin_amdgcn_readfirstlane(qidx[u]);   // wave-uniform -> scalar loads
        const float4* qp = (const float4*)(Qb + (size_t)b*BSTR_ + (size_t)qi*STRIDE_ + h*D_);
        float a0=0.f, a1=0.f, a2=0.f, a3=0.f;
        #pragma unroll
        for (int c = 0; c < 16; c++){
            float4 qv = qp[c];
            a0 = fmaf(qv.x, kf[c].x, a0);
            a1 = fmaf(qv.y, kf[c].y, a1);
            a2 = fmaf(qv.z, kf[c].z, a2);
            a3 = fmaf(qv.w, kf[c].w, a3);
        }
        S[u][t] = ((a0+a1)+(a2+a3)) * 0.125f;
    }
    __syncthreads();

    // Phase 2: per-u softmax partial over 256 scores (one wave per u).
    int wv = t >> 6, lane = t & 63;
    for (int u = wv; u < nu; u += 4){
        float4 sv = *(const float4*)&S[u][lane*4];
        float m = fmaxf(fmaxf(sv.x, sv.y), fmaxf(sv.z, sv.w));
        #pragma unroll
        for (int off = 1; off < 64; off <<= 1) m = fmaxf(m, __shfl_xor(m, off));
        float e0 = __expf(sv.x - m), e1 = __expf(sv.y - m);
        float e2 = __expf(sv.z - m), e3 = __expf(sv.w - m);
        float ls = (e0+e1)+(e2+e3);
        #pragma unroll
        for (int off = 1; off < 64; off <<= 1) ls += __shfl_xor(ls, off);
        float4 pv; pv.x = e0; pv.y = e1; pv.z = e2; pv.w = e3;
        *(float4*)&S[u][lane*4] = pv;
        if (lane == 0){
            size_t mi = ((size_t)(bh*KC_ + kc)*U_ + u0 + u)*2;
            mlG[mi] = m; mlG[mi+1] = ls;
        }
    }
    __syncthreads();

    // Phase 3: d-major, shuffle-free. lane d owns output column d;
    // wave w owns u rows [w*6, w*6+6). k-reduction thread-local.
    int d = lane, w = wv;
    int ub = w*6;
    int nuw = nu - ub; if (nuw > 6) nuw = 6; if (nuw < 0) nuw = 0;
    float acc[6];
    #pragma unroll
    for (int j = 0; j < 6; j++) acc[j] = 0.f;
    float vsum = 0.f;
    const float* Vbase = Vb + (size_t)b*BSTR_ + (size_t)(kc*256)*STRIDE_ + h*D_ + d;
    for (int kb = 0; kb < 64; kb++){
        // V[k][d] for 4 consecutive k: wave-coalesced 256 B row reads
        float v0 = Vbase[(size_t)(kb*4+0)*STRIDE_];
        float v1 = Vbase[(size_t)(kb*4+1)*STRIDE_];
        float v2 = Vbase[(size_t)(kb*4+2)*STRIDE_];
        float v3 = Vbase[(size_t)(kb*4+3)*STRIDE_];
        if (uh == 0 && w == 0) vsum += (v0+v1)+(v2+v3);
        #pragma unroll
        for (int j = 0; j < 6; j++){
            float4 p = *(const float4*)&S[ub+j][kb*4];   // wave-uniform broadcast
            acc[j] = fmaf(p.x, v0, acc[j]);
            acc[j] = fmaf(p.y, v1, acc[j]);
            acc[j] = fmaf(p.z, v2, acc[j]);
            acc[j] = fmaf(p.w, v3, acc[j]);
        }
    }
    for (int j = 0; j < nuw; j++)
        Opart[((size_t)(bh*KC_ + kc)*U_ + u0 + ub + j)*64 + d] = acc[j];
    // V column-sum -> mean (SUM). Only uh==0, wave 0 contributes.
    if (uh == 0 && w == 0)
        atomicAdd(&mean[bh*64 + d], vsum);
}

// ---------- fused output: mean fill + split-k merge scatter ----------
__global__ __launch_bounds__(256) void kOut(const float* __restrict__ mean,
                                            const int*   __restrict__ selRow,
                                            const float* __restrict__ mlG,
                                            const float* __restrict__ Opart,
                                            float* __restrict__ out){
    size_t t = (size_t)blockIdx.x*256 + threadIdx.x;   // one float4; 2,097,152 total
    int d16 = (int)(t & 15); int h = (int)((t >> 4) & 7);
    int l   = (int)((t >> 7) & 4095); int b = (int)(t >> 19);
    int bh = b*8 + h;
    int sel = selRow[(size_t)bh*L_ + l];
    float4 o;
    if (sel == 0){
        o = *(const float4*)(mean + bh*64 + d16*4);
        const float inv = 1.0f / L_;
        o.x *= inv; o.y *= inv; o.z *= inv; o.w *= inv;
    } else {
        int u = sel - 1;
        float mstar = -1e30f;
        #pragma unroll
        for (int kc = 0; kc < KC_; kc++)
            mstar = fmaxf(mstar, mlG[((size_t)(bh*KC_ + kc)*U_ + u)*2]);
        float lsum = 0.f;
        float4 acc; acc.x = acc.y = acc.z = acc.w = 0.f;
        #pragma unroll
        for (int kc = 0; kc < KC_; kc++){
            size_t mi = ((size_t)(bh*KC_ + kc)*U_ + u)*2;
            float w = __expf(mlG[mi] - mstar);
            lsum = fmaf(mlG[mi+1], w, lsum);
            float4 op = *(const float4*)(Opart + ((size_t)(bh*KC_ + kc)*U_ + u)*64 + d16*4);
            acc.x = fmaf(w, op.x, acc.x);
            acc.y = fmaf(w, op.y, acc.y);
            acc.z = fmaf(w, op.z, acc.z);
            acc.w = fmaf(w, op.w, acc.w);
        }
        float inv = 1.0f / lsum;
        acc.x *= inv; acc.y *= inv; acc.z *= inv; acc.w *= inv;
        o = acc;
    }
    ((float4*)out)[t] = o;
}

extern "C" void kernel_launch(void* const* d_in, const int* in_sizes, int n_in,
                              void* d_out, int out_size, void* d_ws, size_t ws_size,
                              hipStream_t stream) {
    const float* Qb  = (const float*)d_in[0];
    const float* Kb  = (const float*)d_in[1];
    const float* Vb  = (const float*)d_in[2];
    const int*   idx = (const int*)d_in[3];
    float* out = (float*)d_out;

    float* ws = (float*)d_ws;
    // ws layout (float offsets)
    float* M      = ws;                      // 131072
    int*   Mtop   = (int*)(ws + 131072);     // 1440 (pad 2048)
    float* mean   = ws + 133120;             // 2048 (SUM; zeroed in kTopF, scaled in kOut)
    int*   selRow = (int*)(ws + 135168);     // 131072
    float* mlG    = ws + 266240;             // 32*16*45*2 = 46080 (pad 49152)
    float* Opart  = ws + 315392;             // 32*16*45*64 = 1474560
    // total = 1,789,952 floats = 7.2 MB

    kM        <<<dim3(2048),       dim3(256), 0, stream>>>(Qb, Kb, idx, M);
    kTopF     <<<dim3(32),         dim3(512), 0, stream>>>(M, Mtop, mean, selRow);
    kAttnPart <<<dim3(KC_, 32, 2), dim3(256), 0, stream>>>(Qb, Kb, Vb, Mtop, Opart, mlG, mean);
    kOut      <<<dim3(8192),       dim3(256), 0, stream>>>(mean, selRow, mlG, Opart, out);
}

// Round 6
// 343.349 us; speedup vs baseline: 1.0227x; 1.0227x over previous
//
#include <hip/hip_runtime.h>
#include <stdint.h>

#define B_ 4
#define L_ 4096
#define H_ 8
#define D_ 64
#define S_ 45
#define U_ 45
#define BH_ 32
#define KC_ 16                     // split-k chunks (256 keys each)
#define STRIDE_ (H_*D_)            // 512 floats between consecutive l
#define BSTR_ ((size_t)L_*H_*D_)   // 2097152 floats per batch

// index_sample declared int64 in the reference; harness may pass int32 or int64.
__device__ __forceinline__ bool detect_idx64(const int* idxp){
    bool z = true;
    #pragma unroll
    for (int i = 1; i < 32; i += 2) z = z && (idxp[i] == 0);
    return z;
}

// Nontemporal float4 load (HIP float4 is a struct; go through ext_vector).
typedef float v4f_ __attribute__((ext_vector_type(4)));
__device__ __forceinline__ float4 ntload4(const float4* p){
    v4f_ v = __builtin_nontemporal_load((const v4f_*)p);
    return make_float4(v.x, v.y, v.z, v.w);
}

// ---------- kernel A: M[bh][q] = max_s(dot) - sum_s(dot)/L ----------
// 4-head-fused gather (ROUND-4 BEST — reverted from 8-head which thrashed L2):
// one sample row = K[b, ki, hg*4 .. hg*4+3, :] = 1 KB contiguous. One (b,hg)
// per XCD via g&7 -> 4.0 MB hot K slice == L2 size (the cliff: 8 MB thrashes,
// FETCH 46->393 MB, kM 77->117 us). At 77 us = 2.45 TB/s/XCD = 57% of the
// per-XCD L2 service ceiling; NT hints on read-once traffic are kept (null on
// time, reduce L2 pollution).
__global__ __launch_bounds__(256) void kM(const float* __restrict__ Qb,
                                          const float* __restrict__ Kb,
                                          const int* __restrict__ idxp,
                                          float* __restrict__ Mout){
    int g = blockIdx.x;                 // 0..2047
    int grp8 = g & 7;                   // one (b, head-half) per XCD
    int b  = grp8 >> 1;
    int hg = grp8 & 1;
    int chunk = g >> 3;                 // 0..255
    int q0 = chunk * 16;
    bool idx64 = detect_idx64(idxp);

    __shared__ int lidx[16*S_];         // 2.88 KB: this block's 16 q x 45 idx
    for (int i = threadIdx.x; i < 16*S_; i += 256)
        lidx[i] = idx64 ? __builtin_nontemporal_load(&idxp[2*(q0*S_ + i)])
                        : __builtin_nontemporal_load(&idxp[q0*S_ + i]);
    __syncthreads();

    int lane = threadIdx.x & 63;
    int w    = threadIdx.x >> 6;        // wave 0..3
    int grp  = lane >> 4;               // 16-lane group: one q each
    int l16  = lane & 15;
    int ql   = w*4 + grp;               // 0..15
    int q    = q0 + ql;

    const float4* qr = (const float4*)(Qb + (size_t)b*BSTR_ + (size_t)q*STRIDE_ + hg*256);
    float4 qf0 = ntload4(qr + l16);        // head hg*4+0, dims l16*4..+3
    float4 qf1 = ntload4(qr + 16 + l16);   // head hg*4+1
    float4 qf2 = ntload4(qr + 32 + l16);   // head hg*4+2
    float4 qf3 = ntload4(qr + 48 + l16);   // head hg*4+3

    const float* kbase = Kb + (size_t)b*BSTR_ + hg*256;
    // lane<8 of each group accumulates heads {0,1}; lane>=8 heads {2,3}
    float mxa = -1e30f, mxb = -1e30f, sma = 0.f, smb = 0.f;
    const int* myIdx = &lidx[ql*S_];

    #pragma unroll 3
    for (int s = 0; s < S_; s++){
        int ki = myIdx[s];              // broadcast within group
        const float4* kr = (const float4*)(kbase + (size_t)ki*STRIDE_);
        float4 k0 = kr[l16], k1 = kr[16+l16], k2 = kr[32+l16], k3 = kr[48+l16];
        float p0 = qf0.x*k0.x; p0 = fmaf(qf0.y,k0.y,p0); p0 = fmaf(qf0.z,k0.z,p0); p0 = fmaf(qf0.w,k0.w,p0);
        float p1 = qf1.x*k1.x; p1 = fmaf(qf1.y,k1.y,p1); p1 = fmaf(qf1.z,k1.z,p1); p1 = fmaf(qf1.w,k1.w,p1);
        float p2 = qf2.x*k2.x; p2 = fmaf(qf2.y,k2.y,p2); p2 = fmaf(qf2.z,k2.z,p2); p2 = fmaf(qf2.w,k2.w,p2);
        float p3 = qf3.x*k3.x; p3 = fmaf(qf3.y,k3.y,p3); p3 = fmaf(qf3.z,k3.z,p3); p3 = fmaf(qf3.w,k3.w,p3);
        // fold the two 8-lane halves of each head partial (1 shfl each)
        float u0 = p0 + __shfl_xor(p0, 8);
        float u1 = p1 + __shfl_xor(p1, 8);
        float u2 = p2 + __shfl_xor(p2, 8);
        float u3 = p3 + __shfl_xor(p3, 8);
        // lane specialization: low half carries heads 0/1, high half 2/3
        float va = (l16 < 8) ? u0 : u2;
        float vb = (l16 < 8) ? u1 : u3;
        #pragma unroll
        for (int off = 1; off < 8; off <<= 1){
            va += __shfl_xor(va, off);
            vb += __shfl_xor(vb, off);
        }
        mxa = fmaxf(mxa, va); sma += va;
        mxb = fmaxf(mxb, vb); smb += vb;
    }
    // writers: l16==0 -> head0(a), l16==1 -> head1(b), l16==8 -> head2(a), l16==9 -> head3(b)
    int hsel = (l16==0) ? 0 : (l16==1) ? 1 : (l16==8) ? 2 : (l16==9) ? 3 : -1;
    if (hsel >= 0){
        float mv = (l16 & 1) ? mxb : mxa;
        float sv = (l16 & 1) ? smb : sma;
        __builtin_nontemporal_store(mv - sv*(1.0f/L_),
            &Mout[(size_t)(b*8 + hg*4 + hsel)*L_ + q]);
    }
}

// ---------- fused top-45 per (b,h) + selRow map + mean zero ----------
__global__ __launch_bounds__(512) void kTopF(const float* __restrict__ M,
                                             int* __restrict__ Mtop,
                                             float* __restrict__ meanZ,
                                             int* __restrict__ selRow){
    int bh = blockIdx.x;
    int t = threadIdx.x;
    if (t < 64) meanZ[bh*64 + t] = 0.f;
    for (int j = t; j < L_; j += 512) selRow[(size_t)bh*L_ + j] = 0;

    __shared__ float cV[8*U_];
    __shared__ int   cI[8*U_];
    int wv = t >> 6, lane = t & 63;      // wv = segment 0..7
    const float* Mr = M + (size_t)bh*L_ + wv*512;
    float v[8];
    #pragma unroll
    for (int j = 0; j < 8; j++) v[j] = Mr[lane + 64*j];

    for (int it = 0; it < U_; it++){
        float best = -1e30f; int bidx = 0x7fffffff;
        #pragma unroll
        for (int j = 0; j < 8; j++){
            int id = lane + 64*j;
            if (v[j] > best){ best = v[j]; bidx = id; }   // ascending id scan
        }
        #pragma unroll
        for (int off = 1; off < 64; off <<= 1){
            float ov = __shfl_xor(best, off); int oi = __shfl_xor(bidx, off);
            if (ov > best || (ov == best && oi < bidx)){ best = ov; bidx = oi; }
        }
        if (lane == 0){ cV[wv*U_ + it] = best; cI[wv*U_ + it] = wv*512 + bidx; }
        if (lane == (bidx & 63)) v[bidx >> 6] = -1e30f;
    }
    __syncthreads();
    if (t < 64){
        float v2[6]; int id2[6];
        #pragma unroll
        for (int j = 0; j < 6; j++){
            int slot = t + 64*j;
            if (slot < 8*U_){ v2[j] = cV[slot]; id2[j] = cI[slot]; }
            else            { v2[j] = -1e30f;  id2[j] = 0x7fffffff; }
        }
        for (int it = 0; it < U_; it++){
            float best = -1e30f; int bidx = 0x7fffffff; int bj = 0;
            #pragma unroll
            for (int j = 0; j < 6; j++){
                if (v2[j] > best || (v2[j] == best && id2[j] < bidx)){
                    best = v2[j]; bidx = id2[j]; bj = j;
                }
            }
            float myBest = best; int myIdx = bidx;
            #pragma unroll
            for (int off = 1; off < 64; off <<= 1){
                float ov = __shfl_xor(best, off); int oi = __shfl_xor(bidx, off);
                if (ov > best || (ov == best && oi < bidx)){ best = ov; bidx = oi; }
            }
            if (t == 0){
                Mtop[bh*U_ + it] = bidx;
                selRow[(size_t)bh*L_ + bidx] = it + 1;
            }
            if (myBest == best && myIdx == bidx) v2[bj] = -1e30f;  // unique owner
        }
    }
}

// ---------- fused flash split-k: scores + softmax partials + PV + V-sum ----------
// uh FUSED: one block per (kc,bh) handles ALL 45 u-rows, so the 256-key K
// chunk is register-staged ONCE and V streamed ONCE (K+V traffic halved vs
// the uh=2 split; barriers halved). Grid (kc=16, bh=32) = 512 blocks,
// 256 threads, ~50 KB LDS (2 blocks/CU). Phase 3 d-major shuffle-free:
// lane = output column d, wave owns 12 u-rows, P reads are wave-uniform
// ds_read_b128 broadcasts, k-reduction thread-local.
__global__ __launch_bounds__(256) void kAttnPart(const float* __restrict__ Qb,
                                                 const float* __restrict__ Kb,
                                                 const float* __restrict__ Vb,
                                                 const int*   __restrict__ Mtop,
                                                 float* __restrict__ Opart,
                                                 float* __restrict__ mlG,
                                                 float* __restrict__ mean){
    int bh = blockIdx.y, b = bh >> 3, h = bh & 7;
    int kc = blockIdx.x;
    int t = threadIdx.x;
    __shared__ float S[48][260];          // 49.9 KB (rows >= 45 zeroed scratch)
    __shared__ int   qidx[U_];

    if (t < U_) qidx[t] = Mtop[bh*U_ + t];
    // zero scratch rows 45..47 so phase-3 over-read rows contribute 0 (no NaN)
    for (int i = t; i < 3*260; i += 256) (&S[U_][0])[i] = 0.f;
    __syncthreads();

    // Phase 1: scores for this block's 256 keys, all 45 queries.
    int k = kc*256 + t;
    float4 kf[16];
    const float4* K4 = (const float4*)(Kb + (size_t)b*BSTR_ + (size_t)k*STRIDE_ + h*D_);
    #pragma unroll
    for (int c = 0; c < 16; c++) kf[c] = K4[c];
    for (int u = 0; u < U_; u++){
        int qi = __builtin_amdgcn_readfirstlane(qidx[u]);   // wave-uniform -> scalar loads
        const float4* qp = (const float4*)(Qb + (size_t)b*BSTR_ + (size_t)qi*STRIDE_ + h*D_);
        float a0=0.f, a1=0.f, a2=0.f, a3=0.f;
        #pragma unroll
        for (int c = 0; c < 16; c++){
            float4 qv = qp[c];
            a0 = fmaf(qv.x, kf[c].x, a0);
            a1 = fmaf(qv.y, kf[c].y, a1);
            a2 = fmaf(qv.z, kf[c].z, a2);
            a3 = fmaf(qv.w, kf[c].w, a3);
        }
        S[u][t] = ((a0+a1)+(a2+a3)) * 0.125f;
    }
    __syncthreads();

    // Phase 2: per-u softmax partial over 256 scores (one wave per u).
    int wv = t >> 6, lane = t & 63;
    for (int u = wv; u < U_; u += 4){
        float4 sv = *(const float4*)&S[u][lane*4];
        float m = fmaxf(fmaxf(sv.x, sv.y), fmaxf(sv.z, sv.w));
        #pragma unroll
        for (int off = 1; off < 64; off <<= 1) m = fmaxf(m, __shfl_xor(m, off));
        float e0 = __expf(sv.x - m), e1 = __expf(sv.y - m);
        float e2 = __expf(sv.z - m), e3 = __expf(sv.w - m);
        float ls = (e0+e1)+(e2+e3);
        #pragma unroll
        for (int off = 1; off < 64; off <<= 1) ls += __shfl_xor(ls, off);
        float4 pv; pv.x = e0; pv.y = e1; pv.z = e2; pv.w = e3;
        *(float4*)&S[u][lane*4] = pv;
        if (lane == 0){
            size_t mi = ((size_t)(bh*KC_ + kc)*U_ + u)*2;
            mlG[mi] = m; mlG[mi+1] = ls;
        }
    }
    __syncthreads();

    // Phase 3: d-major, shuffle-free. lane d owns output column d;
    // wave w owns u rows [w*12, w*12+12). k-reduction thread-local.
    int d = lane, w = wv;
    int ub = w*12;
    int nuw = U_ - ub; if (nuw > 12) nuw = 12;
    float acc[12];
    #pragma unroll
    for (int j = 0; j < 12; j++) acc[j] = 0.f;
    float vsum = 0.f;
    const float* Vbase = Vb + (size_t)b*BSTR_ + (size_t)(kc*256)*STRIDE_ + h*D_ + d;
    for (int kb = 0; kb < 64; kb++){
        // V[k][d] for 4 consecutive k: wave-coalesced 256 B row reads
        float v0 = Vbase[(size_t)(kb*4+0)*STRIDE_];
        float v1 = Vbase[(size_t)(kb*4+1)*STRIDE_];
        float v2 = Vbase[(size_t)(kb*4+2)*STRIDE_];
        float v3 = Vbase[(size_t)(kb*4+3)*STRIDE_];
        if (w == 0) vsum += (v0+v1)+(v2+v3);
        #pragma unroll
        for (int j = 0; j < 12; j++){
            float4 p = *(const float4*)&S[ub+j][kb*4];   // wave-uniform broadcast
            acc[j] = fmaf(p.x, v0, acc[j]);
            acc[j] = fmaf(p.y, v1, acc[j]);
            acc[j] = fmaf(p.z, v2, acc[j]);
            acc[j] = fmaf(p.w, v3, acc[j]);
        }
    }
    for (int j = 0; j < nuw; j++)
        Opart[((size_t)(bh*KC_ + kc)*U_ + ub + j)*64 + d] = acc[j];
    // V column-sum -> mean (SUM). Wave 0 contributes (V streamed once now).
    if (w == 0)
        atomicAdd(&mean[bh*64 + d], vsum);
}

// ---------- fused output: mean fill + split-k merge scatter ----------
__global__ __launch_bounds__(256) void kOut(const float* __restrict__ mean,
                                            const int*   __restrict__ selRow,
                                            const float* __restrict__ mlG,
                                            const float* __restrict__ Opart,
                                            float* __restrict__ out){
    size_t t = (size_t)blockIdx.x*256 + threadIdx.x;   // one float4; 2,097,152 total
    int d16 = (int)(t & 15); int h = (int)((t >> 4) & 7);
    int l   = (int)((t >> 7) & 4095); int b = (int)(t >> 19);
    int bh = b*8 + h;
    int sel = selRow[(size_t)bh*L_ + l];
    float4 o;
    if (sel == 0){
        o = *(const float4*)(mean + bh*64 + d16*4);
        const float inv = 1.0f / L_;
        o.x *= inv; o.y *= inv; o.z *= inv; o.w *= inv;
    } else {
        int u = sel - 1;
        float mstar = -1e30f;
        #pragma unroll
        for (int kc = 0; kc < KC_; kc++)
            mstar = fmaxf(mstar, mlG[((size_t)(bh*KC_ + kc)*U_ + u)*2]);
        float lsum = 0.f;
        float4 acc; acc.x = acc.y = acc.z = acc.w = 0.f;
        #pragma unroll
        for (int kc = 0; kc < KC_; kc++){
            size_t mi = ((size_t)(bh*KC_ + kc)*U_ + u)*2;
            float w = __expf(mlG[mi] - mstar);
            lsum = fmaf(mlG[mi+1], w, lsum);
            float4 op = *(const float4*)(Opart + ((size_t)(bh*KC_ + kc)*U_ + u)*64 + d16*4);
            acc.x = fmaf(w, op.x, acc.x);
            acc.y = fmaf(w, op.y, acc.y);
            acc.z = fmaf(w, op.z, acc.z);
            acc.w = fmaf(w, op.w, acc.w);
        }
        float inv = 1.0f / lsum;
        acc.x *= inv; acc.y *= inv; acc.z *= inv; acc.w *= inv;
        o = acc;
    }
    ((float4*)out)[t] = o;
}

extern "C" void kernel_launch(void* const* d_in, const int* in_sizes, int n_in,
                              void* d_out, int out_size, void* d_ws, size_t ws_size,
                              hipStream_t stream) {
    const float* Qb  = (const float*)d_in[0];
    const float* Kb  = (const float*)d_in[1];
    const float* Vb  = (const float*)d_in[2];
    const int*   idx = (const int*)d_in[3];
    float* out = (float*)d_out;

    float* ws = (float*)d_ws;
    // ws layout (float offsets)
    float* M      = ws;                      // 131072
    int*   Mtop   = (int*)(ws + 131072);     // 1440 (pad 2048)
    float* mean   = ws + 133120;             // 2048 (SUM; zeroed in kTopF, scaled in kOut)
    int*   selRow = (int*)(ws + 135168);     // 131072
    float* mlG    = ws + 266240;             // 32*16*45*2 = 46080 (pad 49152)
    float* Opart  = ws + 315392;             // 32*16*45*64 = 1474560
    // total = 1,789,952 floats = 7.2 MB

    kM        <<<dim3(2048),     dim3(256), 0, stream>>>(Qb, Kb, idx, M);
    kTopF     <<<dim3(32),       dim3(512), 0, stream>>>(M, Mtop, mean, selRow);
    kAttnPart <<<dim3(KC_, 32),  dim3(256), 0, stream>>>(Qb, Kb, Vb, Mtop, Opart, mlG, mean);
    kOut      <<<dim3(8192),     dim3(256), 0, stream>>>(mean, selRow, mlG, Opart, out);
}

// Round 7
// 308.669 us; speedup vs baseline: 1.1376x; 1.1124x over previous
//
#include <hip/hip_runtime.h>
#include <stdint.h>

#define B_ 4
#define L_ 4096
#define H_ 8
#define D_ 64
#define S_ 45
#define U_ 45
#define BH_ 32
#define KC_ 16                     // split-k chunks (256 keys each)
#define STRIDE_ (H_*D_)            // 512 floats between consecutive l
#define BSTR_ ((size_t)L_*H_*D_)   // 2097152 floats per batch

// index_sample declared int64 in the reference; harness may pass int32 or int64.
__device__ __forceinline__ bool detect_idx64(const int* idxp){
    bool z = true;
    #pragma unroll
    for (int i = 1; i < 32; i += 2) z = z && (idxp[i] == 0);
    return z;
}

// Nontemporal float4 load (HIP float4 is a struct; go through ext_vector).
typedef float v4f_ __attribute__((ext_vector_type(4)));
__device__ __forceinline__ float4 ntload4(const float4* p){
    v4f_ v = __builtin_nontemporal_load((const v4f_*)p);
    return make_float4(v.x, v.y, v.z, v.w);
}

// ---------- kernel A: M[bh][q] = max_s(dot) - sum_s(dot)/L ----------
// 4-head-fused gather (ROUND-4 BEST): one sample row = K[b, ki, hg*4..+3, :]
// = 1 KB contiguous. One (b,hg) per XCD via g&7 -> 4.0 MB hot K slice == L2
// size (8-head/8 MB thrashes: FETCH 46->393 MB, 77->117 us). 77 us =
// 2.45 TB/s/XCD = ~57% per-XCD L2 service rate. NT hints on read-once traffic.
__global__ __launch_bounds__(256) void kM(const float* __restrict__ Qb,
                                          const float* __restrict__ Kb,
                                          const int* __restrict__ idxp,
                                          float* __restrict__ Mout){
    int g = blockIdx.x;                 // 0..2047
    int grp8 = g & 7;                   // one (b, head-half) per XCD
    int b  = grp8 >> 1;
    int hg = grp8 & 1;
    int chunk = g >> 3;                 // 0..255
    int q0 = chunk * 16;
    bool idx64 = detect_idx64(idxp);

    __shared__ int lidx[16*S_];         // 2.88 KB: this block's 16 q x 45 idx
    for (int i = threadIdx.x; i < 16*S_; i += 256)
        lidx[i] = idx64 ? __builtin_nontemporal_load(&idxp[2*(q0*S_ + i)])
                        : __builtin_nontemporal_load(&idxp[q0*S_ + i]);
    __syncthreads();

    int lane = threadIdx.x & 63;
    int w    = threadIdx.x >> 6;        // wave 0..3
    int grp  = lane >> 4;               // 16-lane group: one q each
    int l16  = lane & 15;
    int ql   = w*4 + grp;               // 0..15
    int q    = q0 + ql;

    const float4* qr = (const float4*)(Qb + (size_t)b*BSTR_ + (size_t)q*STRIDE_ + hg*256);
    float4 qf0 = ntload4(qr + l16);        // head hg*4+0, dims l16*4..+3
    float4 qf1 = ntload4(qr + 16 + l16);   // head hg*4+1
    float4 qf2 = ntload4(qr + 32 + l16);   // head hg*4+2
    float4 qf3 = ntload4(qr + 48 + l16);   // head hg*4+3

    const float* kbase = Kb + (size_t)b*BSTR_ + hg*256;
    // lane<8 of each group accumulates heads {0,1}; lane>=8 heads {2,3}
    float mxa = -1e30f, mxb = -1e30f, sma = 0.f, smb = 0.f;
    const int* myIdx = &lidx[ql*S_];

    #pragma unroll 3
    for (int s = 0; s < S_; s++){
        int ki = myIdx[s];              // broadcast within group
        const float4* kr = (const float4*)(kbase + (size_t)ki*STRIDE_);
        float4 k0 = kr[l16], k1 = kr[16+l16], k2 = kr[32+l16], k3 = kr[48+l16];
        float p0 = qf0.x*k0.x; p0 = fmaf(qf0.y,k0.y,p0); p0 = fmaf(qf0.z,k0.z,p0); p0 = fmaf(qf0.w,k0.w,p0);
        float p1 = qf1.x*k1.x; p1 = fmaf(qf1.y,k1.y,p1); p1 = fmaf(qf1.z,k1.z,p1); p1 = fmaf(qf1.w,k1.w,p1);
        float p2 = qf2.x*k2.x; p2 = fmaf(qf2.y,k2.y,p2); p2 = fmaf(qf2.z,k2.z,p2); p2 = fmaf(qf2.w,k2.w,p2);
        float p3 = qf3.x*k3.x; p3 = fmaf(qf3.y,k3.y,p3); p3 = fmaf(qf3.z,k3.z,p3); p3 = fmaf(qf3.w,k3.w,p3);
        // fold the two 8-lane halves of each head partial (1 shfl each)
        float u0 = p0 + __shfl_xor(p0, 8);
        float u1 = p1 + __shfl_xor(p1, 8);
        float u2 = p2 + __shfl_xor(p2, 8);
        float u3 = p3 + __shfl_xor(p3, 8);
        // lane specialization: low half carries heads 0/1, high half 2/3
        float va = (l16 < 8) ? u0 : u2;
        float vb = (l16 < 8) ? u1 : u3;
        #pragma unroll
        for (int off = 1; off < 8; off <<= 1){
            va += __shfl_xor(va, off);
            vb += __shfl_xor(vb, off);
        }
        mxa = fmaxf(mxa, va); sma += va;
        mxb = fmaxf(mxb, vb); smb += vb;
    }
    // writers: l16==0 -> head0(a), l16==1 -> head1(b), l16==8 -> head2(a), l16==9 -> head3(b)
    int hsel = (l16==0) ? 0 : (l16==1) ? 1 : (l16==8) ? 2 : (l16==9) ? 3 : -1;
    if (hsel >= 0){
        float mv = (l16 & 1) ? mxb : mxa;
        float sv = (l16 & 1) ? smb : sma;
        __builtin_nontemporal_store(mv - sv*(1.0f/L_),
            &Mout[(size_t)(b*8 + hg*4 + hsel)*L_ + q]);
    }
}

// ---------- fused top-45 per (b,h) + selRow map + mean zero ----------
__global__ __launch_bounds__(512) void kTopF(const float* __restrict__ M,
                                             int* __restrict__ Mtop,
                                             float* __restrict__ meanZ,
                                             int* __restrict__ selRow){
    int bh = blockIdx.x;
    int t = threadIdx.x;
    if (t < 64) meanZ[bh*64 + t] = 0.f;
    for (int j = t; j < L_; j += 512) selRow[(size_t)bh*L_ + j] = 0;

    __shared__ float cV[8*U_];
    __shared__ int   cI[8*U_];
    int wv = t >> 6, lane = t & 63;      // wv = segment 0..7
    const float* Mr = M + (size_t)bh*L_ + wv*512;
    float v[8];
    #pragma unroll
    for (int j = 0; j < 8; j++) v[j] = Mr[lane + 64*j];

    for (int it = 0; it < U_; it++){
        float best = -1e30f; int bidx = 0x7fffffff;
        #pragma unroll
        for (int j = 0; j < 8; j++){
            int id = lane + 64*j;
            if (v[j] > best){ best = v[j]; bidx = id; }   // ascending id scan
        }
        #pragma unroll
        for (int off = 1; off < 64; off <<= 1){
            float ov = __shfl_xor(best, off); int oi = __shfl_xor(bidx, off);
            if (ov > best || (ov == best && oi < bidx)){ best = ov; bidx = oi; }
        }
        if (lane == 0){ cV[wv*U_ + it] = best; cI[wv*U_ + it] = wv*512 + bidx; }
        if (lane == (bidx & 63)) v[bidx >> 6] = -1e30f;
    }
    __syncthreads();
    if (t < 64){
        float v2[6]; int id2[6];
        #pragma unroll
        for (int j = 0; j < 6; j++){
            int slot = t + 64*j;
            if (slot < 8*U_){ v2[j] = cV[slot]; id2[j] = cI[slot]; }
            else            { v2[j] = -1e30f;  id2[j] = 0x7fffffff; }
        }
        for (int it = 0; it < U_; it++){
            float best = -1e30f; int bidx = 0x7fffffff; int bj = 0;
            #pragma unroll
            for (int j = 0; j < 6; j++){
                if (v2[j] > best || (v2[j] == best && id2[j] < bidx)){
                    best = v2[j]; bidx = id2[j]; bj = j;
                }
            }
            float myBest = best; int myIdx = bidx;
            #pragma unroll
            for (int off = 1; off < 64; off <<= 1){
                float ov = __shfl_xor(best, off); int oi = __shfl_xor(bidx, off);
                if (ov > best || (ov == best && oi < bidx)){ best = ov; bidx = oi; }
            }
            if (t == 0){
                Mtop[bh*U_ + it] = bidx;
                selRow[(size_t)bh*L_ + bidx] = it + 1;
            }
            if (myBest == best && myIdx == bidx) v2[bj] = -1e30f;  // unique owner
        }
    }
}

// ---------- fused flash split-k+u: scores + softmax partials + PV + V-sum ----------
// uh=4 split (round-6 lesson: this kernel is LATENCY-bound at 5% HBM; block
// count is the lever, traffic is not). Grid (kc=16, bh=32, uh=4) = 2048
// blocks, 256 threads, 12.5 KB LDS -> 8 blocks/CU co-resident. Each block:
// 256-key chunk, <=12 of the 45 queries; phase-1 chain 12 u-iters; phase-3
// d-major shuffle-free, wave owns 3 u-rows, P reads wave-uniform broadcasts.
__global__ __launch_bounds__(256) void kAttnPart(const float* __restrict__ Qb,
                                                 const float* __restrict__ Kb,
                                                 const float* __restrict__ Vb,
                                                 const int*   __restrict__ Mtop,
                                                 float* __restrict__ Opart,
                                                 float* __restrict__ mlG,
                                                 float* __restrict__ mean){
    int bh = blockIdx.y, b = bh >> 3, h = bh & 7;
    int kc = blockIdx.x, uh = blockIdx.z;
    int u0 = uh * 12;
    int nu = U_ - u0; if (nu > 12) nu = 12;    // 12,12,12,9
    int t = threadIdx.x;
    __shared__ float S[12][260];          // 12.5 KB (rows >= nu zeroed scratch)
    __shared__ int   qidx[12];

    if (t < nu) qidx[t] = Mtop[bh*U_ + u0 + t];
    // zero scratch rows nu..11 so phase-3 over-read rows contribute 0 (no NaN)
    for (int i = t; i < (12 - nu)*260; i += 256) (&S[nu][0])[i] = 0.f;
    __syncthreads();

    // Phase 1: scores for this block's 256 keys, its nu queries.
    int k = kc*256 + t;
    float4 kf[16];
    const float4* K4 = (const float4*)(Kb + (size_t)b*BSTR_ + (size_t)k*STRIDE_ + h*D_);
    #pragma unroll
    for (int c = 0; c < 16; c++) kf[c] = K4[c];
    for (int u = 0; u < nu; u++){
        int qi = __builtin_amdgcn_readfirstlane(qidx[u]);   // wave-uniform -> scalar loads
        const float4* qp = (const float4*)(Qb + (size_t)b*BSTR_ + (size_t)qi*STRIDE_ + h*D_);
        float a0=0.f, a1=0.f, a2=0.f, a3=0.f;
        #pragma unroll
        for (int c = 0; c < 16; c++){
            float4 qv = qp[c];
            a0 = fmaf(qv.x, kf[c].x, a0);
            a1 = fmaf(qv.y, kf[c].y, a1);
            a2 = fmaf(qv.z, kf[c].z, a2);
            a3 = fmaf(qv.w, kf[c].w, a3);
        }
        S[u][t] = ((a0+a1)+(a2+a3)) * 0.125f;
    }
    __syncthreads();

    // Phase 2: per-u softmax partial over 256 scores (one wave per u).
    int wv = t >> 6, lane = t & 63;
    for (int u = wv; u < nu; u += 4){
        float4 sv = *(const float4*)&S[u][lane*4];
        float m = fmaxf(fmaxf(sv.x, sv.y), fmaxf(sv.z, sv.w));
        #pragma unroll
        for (int off = 1; off < 64; off <<= 1) m = fmaxf(m, __shfl_xor(m, off));
        float e0 = __expf(sv.x - m), e1 = __expf(sv.y - m);
        float e2 = __expf(sv.z - m), e3 = __expf(sv.w - m);
        float ls = (e0+e1)+(e2+e3);
        #pragma unroll
        for (int off = 1; off < 64; off <<= 1) ls += __shfl_xor(ls, off);
        float4 pv; pv.x = e0; pv.y = e1; pv.z = e2; pv.w = e3;
        *(float4*)&S[u][lane*4] = pv;
        if (lane == 0){
            size_t mi = ((size_t)(bh*KC_ + kc)*U_ + u0 + u)*2;
            mlG[mi] = m; mlG[mi+1] = ls;
        }
    }
    __syncthreads();

    // Phase 3: d-major, shuffle-free. lane d owns output column d;
    // wave w owns u rows [w*3, w*3+3). k-reduction thread-local.
    int d = lane, w = wv;
    int ub = w*3;
    int nuw = nu - ub; if (nuw > 3) nuw = 3; if (nuw < 0) nuw = 0;
    float acc[3];
    #pragma unroll
    for (int j = 0; j < 3; j++) acc[j] = 0.f;
    float vsum = 0.f;
    const float* Vbase = Vb + (size_t)b*BSTR_ + (size_t)(kc*256)*STRIDE_ + h*D_ + d;
    for (int kb = 0; kb < 64; kb++){
        // V[k][d] for 4 consecutive k: wave-coalesced 256 B row reads
        float v0 = Vbase[(size_t)(kb*4+0)*STRIDE_];
        float v1 = Vbase[(size_t)(kb*4+1)*STRIDE_];
        float v2 = Vbase[(size_t)(kb*4+2)*STRIDE_];
        float v3 = Vbase[(size_t)(kb*4+3)*STRIDE_];
        if (uh == 0 && w == 0) vsum += (v0+v1)+(v2+v3);
        #pragma unroll
        for (int j = 0; j < 3; j++){
            float4 p = *(const float4*)&S[ub+j][kb*4];   // wave-uniform broadcast
            acc[j] = fmaf(p.x, v0, acc[j]);
            acc[j] = fmaf(p.y, v1, acc[j]);
            acc[j] = fmaf(p.z, v2, acc[j]);
            acc[j] = fmaf(p.w, v3, acc[j]);
        }
    }
    for (int j = 0; j < nuw; j++)
        Opart[((size_t)(bh*KC_ + kc)*U_ + u0 + ub + j)*64 + d] = acc[j];
    // V column-sum -> mean (SUM). Only uh==0, wave 0 contributes.
    if (uh == 0 && w == 0)
        atomicAdd(&mean[bh*64 + d], vsum);
}

// ---------- fused output: mean fill + split-k merge scatter ----------
__global__ __launch_bounds__(256) void kOut(const float* __restrict__ mean,
                                            const int*   __restrict__ selRow,
                                            const float* __restrict__ mlG,
                                            const float* __restrict__ Opart,
                                            float* __restrict__ out){
    size_t t = (size_t)blockIdx.x*256 + threadIdx.x;   // one float4; 2,097,152 total
    int d16 = (int)(t & 15); int h = (int)((t >> 4) & 7);
    int l   = (int)((t >> 7) & 4095); int b = (int)(t >> 19);
    int bh = b*8 + h;
    int sel = selRow[(size_t)bh*L_ + l];
    float4 o;
    if (sel == 0){
        o = *(const float4*)(mean + bh*64 + d16*4);
        const float inv = 1.0f / L_;
        o.x *= inv; o.y *= inv; o.z *= inv; o.w *= inv;
    } else {
        int u = sel - 1;
        float mstar = -1e30f;
        #pragma unroll
        for (int kc = 0; kc < KC_; kc++)
            mstar = fmaxf(mstar, mlG[((size_t)(bh*KC_ + kc)*U_ + u)*2]);
        float lsum = 0.f;
        float4 acc; acc.x = acc.y = acc.z = acc.w = 0.f;
        #pragma unroll
        for (int kc = 0; kc < KC_; kc++){
            size_t mi = ((size_t)(bh*KC_ + kc)*U_ + u)*2;
            float w = __expf(mlG[mi] - mstar);
            lsum = fmaf(mlG[mi+1], w, lsum);
            float4 op = *(const float4*)(Opart + ((size_t)(bh*KC_ + kc)*U_ + u)*64 + d16*4);
            acc.x = fmaf(w, op.x, acc.x);
            acc.y = fmaf(w, op.y, acc.y);
            acc.z = fmaf(w, op.z, acc.z);
            acc.w = fmaf(w, op.w, acc.w);
        }
        float inv = 1.0f / lsum;
        acc.x *= inv; acc.y *= inv; acc.z *= inv; acc.w *= inv;
        o = acc;
    }
    ((float4*)out)[t] = o;
}

extern "C" void kernel_launch(void* const* d_in, const int* in_sizes, int n_in,
                              void* d_out, int out_size, void* d_ws, size_t ws_size,
                              hipStream_t stream) {
    const float* Qb  = (const float*)d_in[0];
    const float* Kb  = (const float*)d_in[1];
    const float* Vb  = (const float*)d_in[2];
    const int*   idx = (const int*)d_in[3];
    float* out = (float*)d_out;

    float* ws = (float*)d_ws;
    // ws layout (float offsets)
    float* M      = ws;                      // 131072
    int*   Mtop   = (int*)(ws + 131072);     // 1440 (pad 2048)
    float* mean   = ws + 133120;             // 2048 (SUM; zeroed in kTopF, scaled in kOut)
    int*   selRow = (int*)(ws + 135168);     // 131072
    float* mlG    = ws + 266240;             // 32*16*45*2 = 46080 (pad 49152)
    float* Opart  = ws + 315392;             // 32*16*45*64 = 1474560
    // total = 1,789,952 floats = 7.2 MB

    kM        <<<dim3(2048),        dim3(256), 0, stream>>>(Qb, Kb, idx, M);
    kTopF     <<<dim3(32),          dim3(512), 0, stream>>>(M, Mtop, mean, selRow);
    kAttnPart <<<dim3(KC_, 32, 4),  dim3(256), 0, stream>>>(Qb, Kb, Vb, Mtop, Opart, mlG, mean);
    kOut      <<<dim3(8192),        dim3(256), 0, stream>>>(mean, selRow, mlG, Opart, out);
}

// Round 8
// 299.571 us; speedup vs baseline: 1.1722x; 1.0304x over previous
//
#include <hip/hip_runtime.h>
#include <stdint.h>

#define B_ 4
#define L_ 4096
#define H_ 8
#define D_ 64
#define S_ 45
#define U_ 45
#define BH_ 32
#define KC_ 16                     // split-k chunks (256 keys each)
#define STRIDE_ (H_*D_)            // 512 floats between consecutive l
#define BSTR_ ((size_t)L_*H_*D_)   // 2097152 floats per batch

// index_sample declared int64 in the reference; harness may pass int32 or int64.
__device__ __forceinline__ bool detect_idx64(const int* idxp){
    bool z = true;
    #pragma unroll
    for (int i = 1; i < 32; i += 2) z = z && (idxp[i] == 0);
    return z;
}

// Nontemporal float4 load (HIP float4 is a struct; go through ext_vector).
typedef float v4f_ __attribute__((ext_vector_type(4)));
__device__ __forceinline__ float4 ntload4(const float4* p){
    v4f_ v = __builtin_nontemporal_load((const v4f_*)p);
    return make_float4(v.x, v.y, v.z, v.w);
}

// ---------- kernel A: M[bh][q] = max_s(dot) - sum_s(dot)/L ----------
// 4-head-fused gather (ROUND-4 BEST): one sample row = K[b, ki, hg*4..+3, :]
// = 1 KB contiguous. One (b,hg) per XCD via g&7 -> 4.0 MB hot K slice == L2
// size (8-head/8 MB thrashes: FETCH 46->393 MB, 77->117 us). 77 us =
// 2.45 TB/s/XCD = ~57% per-XCD L2 service rate. NT hints on read-once traffic.
__global__ __launch_bounds__(256) void kM(const float* __restrict__ Qb,
                                          const float* __restrict__ Kb,
                                          const int* __restrict__ idxp,
                                          float* __restrict__ Mout){
    int g = blockIdx.x;                 // 0..2047
    int grp8 = g & 7;                   // one (b, head-half) per XCD
    int b  = grp8 >> 1;
    int hg = grp8 & 1;
    int chunk = g >> 3;                 // 0..255
    int q0 = chunk * 16;
    bool idx64 = detect_idx64(idxp);

    __shared__ int lidx[16*S_];         // 2.88 KB: this block's 16 q x 45 idx
    for (int i = threadIdx.x; i < 16*S_; i += 256)
        lidx[i] = idx64 ? __builtin_nontemporal_load(&idxp[2*(q0*S_ + i)])
                        : __builtin_nontemporal_load(&idxp[q0*S_ + i]);
    __syncthreads();

    int lane = threadIdx.x & 63;
    int w    = threadIdx.x >> 6;        // wave 0..3
    int grp  = lane >> 4;               // 16-lane group: one q each
    int l16  = lane & 15;
    int ql   = w*4 + grp;               // 0..15
    int q    = q0 + ql;

    const float4* qr = (const float4*)(Qb + (size_t)b*BSTR_ + (size_t)q*STRIDE_ + hg*256);
    float4 qf0 = ntload4(qr + l16);        // head hg*4+0, dims l16*4..+3
    float4 qf1 = ntload4(qr + 16 + l16);   // head hg*4+1
    float4 qf2 = ntload4(qr + 32 + l16);   // head hg*4+2
    float4 qf3 = ntload4(qr + 48 + l16);   // head hg*4+3

    const float* kbase = Kb + (size_t)b*BSTR_ + hg*256;
    // lane<8 of each group accumulates heads {0,1}; lane>=8 heads {2,3}
    float mxa = -1e30f, mxb = -1e30f, sma = 0.f, smb = 0.f;
    const int* myIdx = &lidx[ql*S_];

    #pragma unroll 3
    for (int s = 0; s < S_; s++){
        int ki = myIdx[s];              // broadcast within group
        const float4* kr = (const float4*)(kbase + (size_t)ki*STRIDE_);
        float4 k0 = kr[l16], k1 = kr[16+l16], k2 = kr[32+l16], k3 = kr[48+l16];
        float p0 = qf0.x*k0.x; p0 = fmaf(qf0.y,k0.y,p0); p0 = fmaf(qf0.z,k0.z,p0); p0 = fmaf(qf0.w,k0.w,p0);
        float p1 = qf1.x*k1.x; p1 = fmaf(qf1.y,k1.y,p1); p1 = fmaf(qf1.z,k1.z,p1); p1 = fmaf(qf1.w,k1.w,p1);
        float p2 = qf2.x*k2.x; p2 = fmaf(qf2.y,k2.y,p2); p2 = fmaf(qf2.z,k2.z,p2); p2 = fmaf(qf2.w,k2.w,p2);
        float p3 = qf3.x*k3.x; p3 = fmaf(qf3.y,k3.y,p3); p3 = fmaf(qf3.z,k3.z,p3); p3 = fmaf(qf3.w,k3.w,p3);
        // fold the two 8-lane halves of each head partial (1 shfl each)
        float u0 = p0 + __shfl_xor(p0, 8);
        float u1 = p1 + __shfl_xor(p1, 8);
        float u2 = p2 + __shfl_xor(p2, 8);
        float u3 = p3 + __shfl_xor(p3, 8);
        // lane specialization: low half carries heads 0/1, high half 2/3
        float va = (l16 < 8) ? u0 : u2;
        float vb = (l16 < 8) ? u1 : u3;
        #pragma unroll
        for (int off = 1; off < 8; off <<= 1){
            va += __shfl_xor(va, off);
            vb += __shfl_xor(vb, off);
        }
        mxa = fmaxf(mxa, va); sma += va;
        mxb = fmaxf(mxb, vb); smb += vb;
    }
    // writers: l16==0 -> head0(a), l16==1 -> head1(b), l16==8 -> head2(a), l16==9 -> head3(b)
    int hsel = (l16==0) ? 0 : (l16==1) ? 1 : (l16==8) ? 2 : (l16==9) ? 3 : -1;
    if (hsel >= 0){
        float mv = (l16 & 1) ? mxb : mxa;
        float sv = (l16 & 1) ? smb : sma;
        __builtin_nontemporal_store(mv - sv*(1.0f/L_),
            &Mout[(size_t)(b*8 + hg*4 + hsel)*L_ + q]);
    }
}

// ---------- fused top-45 per (b,h) + mean zero (selRow ELIMINATED) ----------
__global__ __launch_bounds__(512) void kTopF(const float* __restrict__ M,
                                             int* __restrict__ Mtop,
                                             float* __restrict__ meanZ){
    int bh = blockIdx.x;
    int t = threadIdx.x;
    if (t < 64) meanZ[bh*64 + t] = 0.f;

    __shared__ float cV[8*U_];
    __shared__ int   cI[8*U_];
    int wv = t >> 6, lane = t & 63;      // wv = segment 0..7
    const float* Mr = M + (size_t)bh*L_ + wv*512;
    float v[8];
    #pragma unroll
    for (int j = 0; j < 8; j++) v[j] = Mr[lane + 64*j];

    for (int it = 0; it < U_; it++){
        float best = -1e30f; int bidx = 0x7fffffff;
        #pragma unroll
        for (int j = 0; j < 8; j++){
            int id = lane + 64*j;
            if (v[j] > best){ best = v[j]; bidx = id; }   // ascending id scan
        }
        #pragma unroll
        for (int off = 1; off < 64; off <<= 1){
            float ov = __shfl_xor(best, off); int oi = __shfl_xor(bidx, off);
            if (ov > best || (ov == best && oi < bidx)){ best = ov; bidx = oi; }
        }
        if (lane == 0){ cV[wv*U_ + it] = best; cI[wv*U_ + it] = wv*512 + bidx; }
        if (lane == (bidx & 63)) v[bidx >> 6] = -1e30f;
    }
    __syncthreads();
    if (t < 64){
        float v2[6]; int id2[6];
        #pragma unroll
        for (int j = 0; j < 6; j++){
            int slot = t + 64*j;
            if (slot < 8*U_){ v2[j] = cV[slot]; id2[j] = cI[slot]; }
            else            { v2[j] = -1e30f;  id2[j] = 0x7fffffff; }
        }
        for (int it = 0; it < U_; it++){
            float best = -1e30f; int bidx = 0x7fffffff; int bj = 0;
            #pragma unroll
            for (int j = 0; j < 6; j++){
                if (v2[j] > best || (v2[j] == best && id2[j] < bidx)){
                    best = v2[j]; bidx = id2[j]; bj = j;
                }
            }
            float myBest = best; int myIdx = bidx;
            #pragma unroll
            for (int off = 1; off < 64; off <<= 1){
                float ov = __shfl_xor(best, off); int oi = __shfl_xor(bidx, off);
                if (ov > best || (ov == best && oi < bidx)){ best = ov; bidx = oi; }
            }
            if (t == 0) Mtop[bh*U_ + it] = bidx;
            if (myBest == best && myIdx == bidx) v2[bj] = -1e30f;  // unique owner
        }
    }
}

// ---------- fused flash split-k+u: scores + softmax partials + PV + V-sum ----------
// R4-BEST config (uh=2, 1024 blocks, ~25 KB LDS; R6 uh=1 regressed to 96 us,
// R7 uh=4 was +4 us vs this). Phase 3 d-major shuffle-free.
__global__ __launch_bounds__(256) void kAttnPart(const float* __restrict__ Qb,
                                                 const float* __restrict__ Kb,
                                                 const float* __restrict__ Vb,
                                                 const int*   __restrict__ Mtop,
                                                 float* __restrict__ Opart,
                                                 float* __restrict__ mlG,
                                                 float* __restrict__ mean){
    int bh = blockIdx.y, b = bh >> 3, h = bh & 7;
    int kc = blockIdx.x, uh = blockIdx.z;
    int u0 = uh ? 23 : 0;
    int nu = uh ? 22 : 23;
    int t = threadIdx.x;
    __shared__ float S[24][260];          // 24.4 KB (rows >= nu zeroed scratch)
    __shared__ int   qidx[23];

    if (t < nu) qidx[t] = Mtop[bh*U_ + u0 + t];
    // zero scratch rows nu..23 so phase-3 over-read rows contribute 0 (no NaN)
    for (int i = t; i < (24 - nu)*260; i += 256) (&S[nu][0])[i] = 0.f;
    __syncthreads();

    // Phase 1: scores for this block's 256 keys, its nu queries.
    int k = kc*256 + t;
    float4 kf[16];
    const float4* K4 = (const float4*)(Kb + (size_t)b*BSTR_ + (size_t)k*STRIDE_ + h*D_);
    #pragma unroll
    for (int c = 0; c < 16; c++) kf[c] = K4[c];
    for (int u = 0; u < nu; u++){
        int qi = __builtin_amdgcn_readfirstlane(qidx[u]);   // wave-uniform -> scalar loads
        const float4* qp = (const float4*)(Qb + (size_t)b*BSTR_ + (size_t)qi*STRIDE_ + h*D_);
        float a0=0.f, a1=0.f, a2=0.f, a3=0.f;
        #pragma unroll
        for (int c = 0; c < 16; c++){
            float4 qv = qp[c];
            a0 = fmaf(qv.x, kf[c].x, a0);
            a1 = fmaf(qv.y, kf[c].y, a1);
            a2 = fmaf(qv.z, kf[c].z, a2);
            a3 = fmaf(qv.w, kf[c].w, a3);
        }
        S[u][t] = ((a0+a1)+(a2+a3)) * 0.125f;
    }
    __syncthreads();

    // Phase 2: per-u softmax partial over 256 scores (one wave per u).
    int wv = t >> 6, lane = t & 63;
    for (int u = wv; u < nu; u += 4){
        float4 sv = *(const float4*)&S[u][lane*4];
        float m = fmaxf(fmaxf(sv.x, sv.y), fmaxf(sv.z, sv.w));
        #pragma unroll
        for (int off = 1; off < 64; off <<= 1) m = fmaxf(m, __shfl_xor(m, off));
        float e0 = __expf(sv.x - m), e1 = __expf(sv.y - m);
        float e2 = __expf(sv.z - m), e3 = __expf(sv.w - m);
        float ls = (e0+e1)+(e2+e3);
        #pragma unroll
        for (int off = 1; off < 64; off <<= 1) ls += __shfl_xor(ls, off);
        float4 pv; pv.x = e0; pv.y = e1; pv.z = e2; pv.w = e3;
        *(float4*)&S[u][lane*4] = pv;
        if (lane == 0){
            size_t mi = ((size_t)(bh*KC_ + kc)*U_ + u0 + u)*2;
            mlG[mi] = m; mlG[mi+1] = ls;
        }
    }
    __syncthreads();

    // Phase 3: d-major, shuffle-free. lane d owns output column d;
    // wave w owns u rows [w*6, w*6+6). k-reduction thread-local.
    int d = lane, w = wv;
    int ub = w*6;
    int nuw = nu - ub; if (nuw > 6) nuw = 6; if (nuw < 0) nuw = 0;
    float acc[6];
    #pragma unroll
    for (int j = 0; j < 6; j++) acc[j] = 0.f;
    float vsum = 0.f;
    const float* Vbase = Vb + (size_t)b*BSTR_ + (size_t)(kc*256)*STRIDE_ + h*D_ + d;
    for (int kb = 0; kb < 64; kb++){
        // V[k][d] for 4 consecutive k: wave-coalesced 256 B row reads
        float v0 = Vbase[(size_t)(kb*4+0)*STRIDE_];
        float v1 = Vbase[(size_t)(kb*4+1)*STRIDE_];
        float v2 = Vbase[(size_t)(kb*4+2)*STRIDE_];
        float v3 = Vbase[(size_t)(kb*4+3)*STRIDE_];
        if (uh == 0 && w == 0) vsum += (v0+v1)+(v2+v3);
        #pragma unroll
        for (int j = 0; j < 6; j++){
            float4 p = *(const float4*)&S[ub+j][kb*4];   // wave-uniform broadcast
            acc[j] = fmaf(p.x, v0, acc[j]);
            acc[j] = fmaf(p.y, v1, acc[j]);
            acc[j] = fmaf(p.z, v2, acc[j]);
            acc[j] = fmaf(p.w, v3, acc[j]);
        }
    }
    for (int j = 0; j < nuw; j++)
        Opart[((size_t)(bh*KC_ + kc)*U_ + u0 + ub + j)*64 + d] = acc[j];
    // V column-sum -> mean (SUM). Only uh==0, wave 0 contributes.
    if (uh == 0 && w == 0)
        atomicAdd(&mean[bh*64 + d], vsum);
}

// ---------- output stage A: unconditional mean broadcast (pure stream) ----------
__global__ __launch_bounds__(256) void kOutMean(const float* __restrict__ mean,
                                                float* __restrict__ out){
    size_t t = (size_t)blockIdx.x*256 + threadIdx.x;   // one float4; 2,097,152 total
    int d16 = (int)(t & 15); int h = (int)((t >> 4) & 7);
    int b   = (int)(t >> 19);
    int bh = b*8 + h;
    float4 o = *(const float4*)(mean + bh*64 + d16*4);
    const float inv = 1.0f / L_;
    o.x *= inv; o.y *= inv; o.z *= inv; o.w *= inv;
    ((float4*)out)[t] = o;
}

// ---------- output stage B: split-k merge scatter of the 1440 selected rows ----------
// One wave per (bh,u): wave-uniform scalar mlG merge over 16 kc; lane d reads
// Opart coalesced (256 B/row) and overwrites out[b][Mtop[bh][u]][h][d].
// Runs after kOutMean in-stream, so the overwrite ordering is guaranteed.
__global__ __launch_bounds__(256) void kOutScatter(const int*   __restrict__ Mtop,
                                                   const float* __restrict__ mlG,
                                                   const float* __restrict__ Opart,
                                                   float* __restrict__ out){
    int gid = blockIdx.x*4 + (threadIdx.x >> 6);   // 0..1439 = bh*U_ + u
    int lane = threadIdx.x & 63;
    int bh = gid / U_, u = gid % U_;
    int b = bh >> 3, h = bh & 7;
    int l = Mtop[bh*U_ + u];                       // wave-uniform
    float mstar = -1e30f;
    #pragma unroll
    for (int kc = 0; kc < KC_; kc++)
        mstar = fmaxf(mstar, mlG[((size_t)(bh*KC_ + kc)*U_ + u)*2]);
    float lsum = 0.f, acc = 0.f;
    #pragma unroll
    for (int kc = 0; kc < KC_; kc++){
        size_t mi = ((size_t)(bh*KC_ + kc)*U_ + u)*2;
        float wgt = __expf(mlG[mi] - mstar);
        lsum = fmaf(mlG[mi+1], wgt, lsum);
        acc  = fmaf(wgt, Opart[((size_t)(bh*KC_ + kc)*U_ + u)*64 + lane], acc);
    }
    out[((size_t)b*L_ + (size_t)l)*STRIDE_ + h*D_ + lane] = acc / lsum;
}

extern "C" void kernel_launch(void* const* d_in, const int* in_sizes, int n_in,
                              void* d_out, int out_size, void* d_ws, size_t ws_size,
                              hipStream_t stream) {
    const float* Qb  = (const float*)d_in[0];
    const float* Kb  = (const float*)d_in[1];
    const float* Vb  = (const float*)d_in[2];
    const int*   idx = (const int*)d_in[3];
    float* out = (float*)d_out;

    float* ws = (float*)d_ws;
    // ws layout (float offsets)
    float* M      = ws;                      // 131072
    int*   Mtop   = (int*)(ws + 131072);     // 1440 (pad 2048)
    float* mean   = ws + 133120;             // 2048 (SUM; zeroed in kTopF, scaled in kOutMean)
    float* mlG    = ws + 266240;             // 32*16*45*2 = 46080 (pad 49152)
    float* Opart  = ws + 315392;             // 32*16*45*64 = 1474560
    // total = 1,789,952 floats = 7.2 MB

    kM         <<<dim3(2048),       dim3(256), 0, stream>>>(Qb, Kb, idx, M);
    kTopF      <<<dim3(32),         dim3(512), 0, stream>>>(M, Mtop, mean);
    kAttnPart  <<<dim3(KC_, 32, 2), dim3(256), 0, stream>>>(Qb, Kb, Vb, Mtop, Opart, mlG, mean);
    kOutMean   <<<dim3(8192),       dim3(256), 0, stream>>>(mean, out);
    kOutScatter<<<dim3(360),        dim3(256), 0, stream>>>(Mtop, mlG, Opart, out);
}